// Round 5
// baseline (1822.393 us; speedup 1.0000x reference)
//
#include <hip/hip_runtime.h>

#define NN 50000
#define NE 800000
#define DIN 128
#define HD 128
#define CD 64
#define NCHUNK ((NN + 1023) / 1024)  // 49

// ---------------- CSR build ----------------
__global__ void zero_cnt(int* __restrict__ cnt) {
    int i = blockIdx.x * blockDim.x + threadIdx.x;
    if (i < NN) cnt[i] = 0;
}

__global__ void count_deg(const int* __restrict__ dst, int* __restrict__ cnt) {
    int e = blockIdx.x * blockDim.x + threadIdx.x;
    if (e < NE) atomicAdd(&cnt[dst[e]], 1);
}

__global__ void dinv_from_cnt(const int* __restrict__ cnt, float* __restrict__ dinv) {
    int i = blockIdx.x * blockDim.x + threadIdx.x;
    if (i < NN) dinv[i] = rsqrtf((float)(cnt[i] + 2));  // +2 self loops
}

// hierarchical exclusive scan: chunk-local scan + chunk totals
__global__ void __launch_bounds__(1024) scan_a(int* __restrict__ cnt, int* __restrict__ sums) {
    __shared__ int wsum[16];
    int t = threadIdx.x;
    int i = blockIdx.x * 1024 + t;
    int v = (i < NN) ? cnt[i] : 0;
    int x = v;
#pragma unroll
    for (int off = 1; off < 64; off <<= 1) {
        int y = __shfl_up(x, off, 64);
        if ((t & 63) >= off) x += y;
    }
    int wid = t >> 6;
    if ((t & 63) == 63) wsum[wid] = x;
    __syncthreads();
    if (t < 16) {
        int s = wsum[t];
#pragma unroll
        for (int off = 1; off < 16; off <<= 1) {
            int y = __shfl_up(s, off, 16);
            if (t >= off) s += y;
        }
        wsum[t] = s;
    }
    __syncthreads();
    int base = (wid > 0) ? wsum[wid - 1] : 0;
    int incl = base + x;
    if (i < NN) cnt[i] = incl - v;  // exclusive within chunk
    if (t == 1023) sums[blockIdx.x] = incl;
}

__global__ void scan_b(int* __restrict__ sums) {
    int t = threadIdx.x;
    int v = (t < NCHUNK) ? sums[t] : 0;
    int x = v;
#pragma unroll
    for (int off = 1; off < 64; off <<= 1) {
        int y = __shfl_up(x, off, 64);
        if (t >= off) x += y;
    }
    if (t < NCHUNK) sums[t] = x - v;  // exclusive chunk bases
}

__global__ void scan_c(int* __restrict__ cnt, const int* __restrict__ sums) {
    int i = blockIdx.x * blockDim.x + threadIdx.x;
    if (i < NN) cnt[i] += sums[i >> 10];
}

// after fill: rowptr[v] == end offset of row v
__global__ void fill_csr(const int* __restrict__ src, const int* __restrict__ dst,
                         int* __restrict__ rowptr, int* __restrict__ col) {
    int e = blockIdx.x * blockDim.x + threadIdx.x;
    if (e < NE) {
        int d = dst[e];
        int pos = atomicAdd(&rowptr[d], 1);
        col[pos] = src[e];
    }
}

// ---------------- GEMM1: hs1 = dinv * (x @ W1), W1 in LDS, 32 rows/block ----------------
__global__ void __launch_bounds__(256) gemm1(const float* __restrict__ x, const float* __restrict__ W1,
                                             const float* __restrict__ dinv, float* __restrict__ hs1) {
    __shared__ float w[DIN * HD];     // 64 KB
    __shared__ float xs[8 * DIN];     // 4 KB
    int t = threadIdx.x;
    {
        float4* wv = (float4*)w;
        const float4* Wg = (const float4*)W1;
#pragma unroll
        for (int i = t; i < DIN * HD / 4; i += 256) wv[i] = Wg[i];
    }
    int half = t >> 7, c = t & 127;
    int rbase = half * 4;
    for (int rr = 0; rr < 4; ++rr) {
        int row0 = blockIdx.x * 32 + rr * 8;
        __syncthreads();
        {
            float4* xv = (float4*)xs;
            int r_of = t >> 5;  // t*4/128
            if (row0 + r_of < NN)
                xv[t] = ((const float4*)&x[(size_t)row0 * DIN])[t];
            else
                xv[t] = make_float4(0.f, 0.f, 0.f, 0.f);
        }
        __syncthreads();
        float a0 = 0.f, a1 = 0.f, a2 = 0.f, a3 = 0.f;
#pragma unroll
        for (int k = 0; k < DIN; ++k) {
            float wv = w[k * HD + c];
            a0 += xs[(rbase + 0) * DIN + k] * wv;
            a1 += xs[(rbase + 1) * DIN + k] * wv;
            a2 += xs[(rbase + 2) * DIN + k] * wv;
            a3 += xs[(rbase + 3) * DIN + k] * wv;
        }
        int row = row0 + rbase;
        if (row + 0 < NN) hs1[(size_t)(row + 0) * HD + c] = a0 * dinv[row + 0];
        if (row + 1 < NN) hs1[(size_t)(row + 1) * HD + c] = a1 * dinv[row + 1];
        if (row + 2 < NN) hs1[(size_t)(row + 2) * HD + c] = a2 * dinv[row + 2];
        if (row + 3 < NN) hs1[(size_t)(row + 3) * HD + c] = a3 * dinv[row + 3];
    }
}

// ---------------- GEMM2: hs2 = dinv * (h1 @ W2), W2 in LDS, 32 rows/block ----------------
__global__ void __launch_bounds__(256) gemm2(const float* __restrict__ h1, const float* __restrict__ W2,
                                             const float* __restrict__ dinv, float* __restrict__ hs2) {
    __shared__ float w[DIN * CD];      // 32 KB
    __shared__ float xs[16 * DIN];     // 8 KB
    int t = threadIdx.x;
    {
        float4* wv = (float4*)w;
        const float4* Wg = (const float4*)W2;
#pragma unroll
        for (int i = t; i < DIN * CD / 4; i += 256) wv[i] = Wg[i];
    }
    int quarter = t >> 6, c = t & 63;
    int rbase = quarter * 4;
    for (int g = 0; g < 2; ++g) {
        int row0 = blockIdx.x * 32 + g * 16;
        __syncthreads();
        {
            float4* xv = (float4*)xs;
            const float4* xg = (const float4*)&h1[(size_t)row0 * DIN];
#pragma unroll
            for (int i = t; i < 512; i += 256) {
                int r_of = i >> 5;
                xv[i] = (row0 + r_of < NN) ? xg[i] : make_float4(0.f, 0.f, 0.f, 0.f);
            }
        }
        __syncthreads();
        float a0 = 0.f, a1 = 0.f, a2 = 0.f, a3 = 0.f;
#pragma unroll
        for (int k = 0; k < DIN; ++k) {
            float wv = w[k * CD + c];
            a0 += xs[(rbase + 0) * DIN + k] * wv;
            a1 += xs[(rbase + 1) * DIN + k] * wv;
            a2 += xs[(rbase + 2) * DIN + k] * wv;
            a3 += xs[(rbase + 3) * DIN + k] * wv;
        }
        int row = row0 + rbase;
        if (row + 0 < NN) hs2[(size_t)(row + 0) * CD + c] = a0 * dinv[row + 0];
        if (row + 1 < NN) hs2[(size_t)(row + 1) * CD + c] = a1 * dinv[row + 1];
        if (row + 2 < NN) hs2[(size_t)(row + 2) * CD + c] = a2 * dinv[row + 2];
        if (row + 3 < NN) hs2[(size_t)(row + 3) * CD + c] = a3 * dinv[row + 3];
    }
}

// ---------------- agg1: CSR gather (float2/lane, one row per wave), unroll 4 ----------------
__global__ void agg1_csr(const int* __restrict__ rowptr, const int* __restrict__ col,
                         const float* __restrict__ hs1, const float* __restrict__ dinv,
                         const float* __restrict__ b1, float* __restrict__ h1) {
    int t = threadIdx.x;
    int v = blockIdx.x * 4 + (t >> 6);
    int c2 = t & 63;  // float2 lane
    const float2* H = (const float2*)hs1;  // row stride 64
    int start = (v == 0) ? 0 : rowptr[v - 1];
    int end = rowptr[v];
    float2 self = H[(size_t)v * 64 + c2];
    float ax = 2.f * self.x, ay = 2.f * self.y;
    int j = start;
    for (; j + 4 <= end; j += 4) {
        int s0 = col[j], s1 = col[j + 1], s2 = col[j + 2], s3 = col[j + 3];
        float2 v0 = H[(size_t)s0 * 64 + c2];
        float2 v1 = H[(size_t)s1 * 64 + c2];
        float2 v2 = H[(size_t)s2 * 64 + c2];
        float2 v3 = H[(size_t)s3 * 64 + c2];
        ax += v0.x + v1.x + v2.x + v3.x;
        ay += v0.y + v1.y + v2.y + v3.y;
    }
    for (; j < end; ++j) {
        float2 u = H[(size_t)col[j] * 64 + c2];
        ax += u.x; ay += u.y;
    }
    float di = dinv[v];
    int c = c2 * 2;
    float2 r;
    r.x = fmaxf(di * ax + b1[c], 0.f);
    r.y = fmaxf(di * ay + b1[c + 1], 0.f);
    ((float2*)h1)[(size_t)v * 64 + c2] = r;
}

// ---------------- agg2: CSR gather + bias + log_softmax (one wave per row), unroll 4 ----------------
__global__ void agg2_csr(const int* __restrict__ rowptr, const int* __restrict__ col,
                         const float* __restrict__ hs2, const float* __restrict__ dinv,
                         const float* __restrict__ b2, float* __restrict__ out) {
    int t = threadIdx.x;
    int v = blockIdx.x * 4 + (t >> 6);
    int c = t & 63;
    int start = (v == 0) ? 0 : rowptr[v - 1];
    int end = rowptr[v];
    float acc = 2.f * hs2[(size_t)v * CD + c];
    int j = start;
    for (; j + 4 <= end; j += 4) {
        int s0 = col[j], s1 = col[j + 1], s2 = col[j + 2], s3 = col[j + 3];
        acc += hs2[(size_t)s0 * CD + c] + hs2[(size_t)s1 * CD + c] +
               hs2[(size_t)s2 * CD + c] + hs2[(size_t)s3 * CD + c];
    }
    for (; j < end; ++j) acc += hs2[(size_t)col[j] * CD + c];
    float o = dinv[v] * acc + b2[c];
    float m = o;
#pragma unroll
    for (int off = 32; off >= 1; off >>= 1) m = fmaxf(m, __shfl_xor(m, off, 64));
    float ex = __expf(o - m);
    float s = ex;
#pragma unroll
    for (int off = 32; off >= 1; off >>= 1) s += __shfl_xor(s, off, 64);
    out[(size_t)v * CD + c] = o - m - __logf(s);
}

extern "C" void kernel_launch(void* const* d_in, const int* in_sizes, int n_in,
                              void* d_out, int out_size, void* d_ws, size_t ws_size,
                              hipStream_t stream) {
    const float* x  = (const float*)d_in[0];
    const int*   ei = (const int*)d_in[1];   // [2, E] int32
    const float* W1 = (const float*)d_in[2];
    const float* b1 = (const float*)d_in[3];
    const float* W2 = (const float*)d_in[4];
    const float* b2 = (const float*)d_in[5];
    float* out = (float*)d_out;

    const int* src = ei;
    const int* dst = ei + NE;

    float* ws = (float*)d_ws;
    float* dinv   = ws;                        // NN floats
    int*   rowptr = (int*)(ws + 65536);        // NN ints
    int*   col    = (int*)(ws + 131072);       // NE ints -> ends at 931072
    int*   sums   = (int*)(ws + 931072);       // 64 ints
    float* hs1    = ws + 933888;               // NN*HD
    float* h1     = ws + 7333888;              // NN*HD
    float* hs2    = hs1;                       // reuse

    // ---- CSR build ----
    zero_cnt<<<(NN + 255) / 256, 256, 0, stream>>>(rowptr);
    count_deg<<<(NE + 255) / 256, 256, 0, stream>>>(dst, rowptr);
    dinv_from_cnt<<<(NN + 255) / 256, 256, 0, stream>>>(rowptr, dinv);
    scan_a<<<NCHUNK, 1024, 0, stream>>>(rowptr, sums);
    scan_b<<<1, 64, 0, stream>>>(sums);
    scan_c<<<(NN + 255) / 256, 256, 0, stream>>>(rowptr, sums);
    fill_csr<<<(NE + 255) / 256, 256, 0, stream>>>(src, dst, rowptr, col);

    // ---- layer 1 ----
    gemm1<<<(NN + 31) / 32, 256, 0, stream>>>(x, W1, dinv, hs1);
    agg1_csr<<<NN / 4, 256, 0, stream>>>(rowptr, col, hs1, dinv, b1, h1);

    // ---- layer 2 ----
    gemm2<<<(NN + 31) / 32, 256, 0, stream>>>(h1, W2, dinv, hs2);
    agg2_csr<<<NN / 4, 256, 0, stream>>>(rowptr, col, hs2, dinv, b2, out);
}

// Round 6
// 321.608 us; speedup vs baseline: 5.6665x; 5.6665x over previous
//
#include <hip/hip_runtime.h>

#define NN 50000
#define NE 800000
#define DIN 128
#define HD 128
#define CD 64
#define NCHUNK ((NN + 1023) / 1024)  // 49

// ---------------- CSR build ----------------
__global__ void count_deg(const int* __restrict__ dst, int* __restrict__ cnt) {
    int e = blockIdx.x * blockDim.x + threadIdx.x;
    if (e < NE) atomicAdd(&cnt[dst[e]], 1);
}

// chunk-local exclusive scan + chunk totals; also emits dinv = rsqrt(cnt+2)
__global__ void __launch_bounds__(1024) scan_a(int* __restrict__ cnt, int* __restrict__ sums,
                                               float* __restrict__ dinv) {
    __shared__ int wsum[16];
    int t = threadIdx.x;
    int i = blockIdx.x * 1024 + t;
    int v = (i < NN) ? cnt[i] : 0;
    if (i < NN) dinv[i] = rsqrtf((float)(v + 2));  // +2 self loops
    int x = v;
#pragma unroll
    for (int off = 1; off < 64; off <<= 1) {
        int y = __shfl_up(x, off, 64);
        if ((t & 63) >= off) x += y;
    }
    int wid = t >> 6;
    if ((t & 63) == 63) wsum[wid] = x;
    __syncthreads();
    if (t < 16) {
        int s = wsum[t];
#pragma unroll
        for (int off = 1; off < 16; off <<= 1) {
            int y = __shfl_up(s, off, 16);
            if (t >= off) s += y;
        }
        wsum[t] = s;
    }
    __syncthreads();
    int base = (wid > 0) ? wsum[wid - 1] : 0;
    int incl = base + x;
    if (i < NN) cnt[i] = incl - v;  // exclusive within chunk
    if (t == 1023) sums[blockIdx.x] = incl;
}

__global__ void scan_b(int* __restrict__ sums) {
    int t = threadIdx.x;
    int v = (t < NCHUNK) ? sums[t] : 0;
    int x = v;
#pragma unroll
    for (int off = 1; off < 64; off <<= 1) {
        int y = __shfl_up(x, off, 64);
        if (t >= off) x += y;
    }
    if (t < NCHUNK) sums[t] = x - v;  // exclusive chunk bases
}

__global__ void scan_c(int* __restrict__ cnt, const int* __restrict__ sums) {
    int i = blockIdx.x * blockDim.x + threadIdx.x;
    if (i < NN) cnt[i] += sums[i >> 10];
}

// after fill: rowptr[v] == end offset of row v (start is rowptr[v-1])
__global__ void fill_csr(const int* __restrict__ src, const int* __restrict__ dst,
                         int* __restrict__ rowptr, int* __restrict__ col) {
    int e = blockIdx.x * blockDim.x + threadIdx.x;
    if (e < NE) {
        int d = dst[e];
        int pos = atomicAdd(&rowptr[d], 1);
        col[pos] = src[e];
    }
}

// ---------------- GEMM1: hs1 = dinv * (x @ W1); W1 in LDS; 8 rows/block ----------------
// unroll capped at 4 to avoid the round-5 VGPR/spill explosion
__global__ void __launch_bounds__(256) gemm1(const float* __restrict__ x, const float* __restrict__ W1,
                                             const float* __restrict__ dinv, float* __restrict__ hs1) {
    __shared__ float w[DIN * HD];   // 64 KB
    __shared__ float xs[8 * DIN];   // 4 KB
    int t = threadIdx.x;
    {
        float4* wv = (float4*)w;
        const float4* Wg = (const float4*)W1;
        for (int i = t; i < DIN * HD / 4; i += 256) wv[i] = Wg[i];
    }
    int row0 = blockIdx.x * 8;  // NN/8 = 6250 exact, no guards
    {
        float4* xv = (float4*)xs;
        int r = t >> 5, q = t & 31;
        xv[t] = ((const float4*)x)[(size_t)(row0 + r) * 32 + q];
    }
    __syncthreads();
    int c = t & 127, half = t >> 7;
    int rbase = half * 4;
    float a0 = 0.f, a1 = 0.f, a2 = 0.f, a3 = 0.f;
#pragma unroll 4
    for (int k = 0; k < DIN; ++k) {
        float wk = w[k * HD + c];
        a0 += xs[(rbase + 0) * DIN + k] * wk;
        a1 += xs[(rbase + 1) * DIN + k] * wk;
        a2 += xs[(rbase + 2) * DIN + k] * wk;
        a3 += xs[(rbase + 3) * DIN + k] * wk;
    }
    int row = row0 + rbase;
    hs1[(size_t)(row + 0) * HD + c] = a0 * dinv[row + 0];
    hs1[(size_t)(row + 1) * HD + c] = a1 * dinv[row + 1];
    hs1[(size_t)(row + 2) * HD + c] = a2 * dinv[row + 2];
    hs1[(size_t)(row + 3) * HD + c] = a3 * dinv[row + 3];
}

// ---------------- GEMM2: hs2 = dinv * (h1 @ W2); W2 in LDS; 16 rows/block ----------------
__global__ void __launch_bounds__(256) gemm2(const float* __restrict__ h1, const float* __restrict__ W2,
                                             const float* __restrict__ dinv, float* __restrict__ hs2) {
    __shared__ float w[DIN * CD];    // 32 KB
    __shared__ float xs[16 * DIN];   // 8 KB
    int t = threadIdx.x;
    {
        float4* wv = (float4*)w;
        const float4* Wg = (const float4*)W2;
        for (int i = t; i < DIN * CD / 4; i += 256) wv[i] = Wg[i];
    }
    int row0 = blockIdx.x * 16;  // NN/16 = 3125 exact
    {
        float4* xv = (float4*)xs;
        const float4* xg = (const float4*)&h1[(size_t)row0 * DIN];
        xv[t] = xg[t];
        xv[t + 256] = xg[t + 256];
    }
    __syncthreads();
    int c = t & 63, quarter = t >> 6;
    int rbase = quarter * 4;
    float a0 = 0.f, a1 = 0.f, a2 = 0.f, a3 = 0.f;
#pragma unroll 4
    for (int k = 0; k < DIN; ++k) {
        float wk = w[k * CD + c];
        a0 += xs[(rbase + 0) * DIN + k] * wk;
        a1 += xs[(rbase + 1) * DIN + k] * wk;
        a2 += xs[(rbase + 2) * DIN + k] * wk;
        a3 += xs[(rbase + 3) * DIN + k] * wk;
    }
    int row = row0 + rbase;
    hs2[(size_t)(row + 0) * CD + c] = a0 * dinv[row + 0];
    hs2[(size_t)(row + 1) * CD + c] = a1 * dinv[row + 1];
    hs2[(size_t)(row + 2) * CD + c] = a2 * dinv[row + 2];
    hs2[(size_t)(row + 3) * CD + c] = a3 * dinv[row + 3];
}

// ---------------- agg1: CSR gather (float2/lane, one row per wave), unroll 4 ----------------
__global__ void agg1_csr(const int* __restrict__ rowptr, const int* __restrict__ col,
                         const float* __restrict__ hs1, const float* __restrict__ dinv,
                         const float* __restrict__ b1, float* __restrict__ h1) {
    int t = threadIdx.x;
    int v = blockIdx.x * 4 + (t >> 6);
    int c2 = t & 63;  // float2 lane
    const float2* H = (const float2*)hs1;  // row stride 64
    int start = (v == 0) ? 0 : rowptr[v - 1];
    int end = rowptr[v];
    float2 self = H[(size_t)v * 64 + c2];
    float ax = 2.f * self.x, ay = 2.f * self.y;
    int j = start;
    for (; j + 4 <= end; j += 4) {
        int s0 = col[j], s1 = col[j + 1], s2 = col[j + 2], s3 = col[j + 3];
        float2 v0 = H[(size_t)s0 * 64 + c2];
        float2 v1 = H[(size_t)s1 * 64 + c2];
        float2 v2 = H[(size_t)s2 * 64 + c2];
        float2 v3 = H[(size_t)s3 * 64 + c2];
        ax += v0.x + v1.x + v2.x + v3.x;
        ay += v0.y + v1.y + v2.y + v3.y;
    }
    for (; j < end; ++j) {
        float2 u = H[(size_t)col[j] * 64 + c2];
        ax += u.x; ay += u.y;
    }
    float di = dinv[v];
    int c = c2 * 2;
    float2 r;
    r.x = fmaxf(di * ax + b1[c], 0.f);
    r.y = fmaxf(di * ay + b1[c + 1], 0.f);
    ((float2*)h1)[(size_t)v * 64 + c2] = r;
}

// ---------------- agg2: CSR gather + bias + log_softmax (one wave per row), unroll 4 ----------------
__global__ void agg2_csr(const int* __restrict__ rowptr, const int* __restrict__ col,
                         const float* __restrict__ hs2, const float* __restrict__ dinv,
                         const float* __restrict__ b2, float* __restrict__ out) {
    int t = threadIdx.x;
    int v = blockIdx.x * 4 + (t >> 6);
    int c = t & 63;
    int start = (v == 0) ? 0 : rowptr[v - 1];
    int end = rowptr[v];
    float acc = 2.f * hs2[(size_t)v * CD + c];
    int j = start;
    for (; j + 4 <= end; j += 4) {
        int s0 = col[j], s1 = col[j + 1], s2 = col[j + 2], s3 = col[j + 3];
        acc += hs2[(size_t)s0 * CD + c] + hs2[(size_t)s1 * CD + c] +
               hs2[(size_t)s2 * CD + c] + hs2[(size_t)s3 * CD + c];
    }
    for (; j < end; ++j) acc += hs2[(size_t)col[j] * CD + c];
    float o = dinv[v] * acc + b2[c];
    float m = o;
#pragma unroll
    for (int off = 32; off >= 1; off >>= 1) m = fmaxf(m, __shfl_xor(m, off, 64));
    float ex = __expf(o - m);
    float s = ex;
#pragma unroll
    for (int off = 32; off >= 1; off >>= 1) s += __shfl_xor(s, off, 64);
    out[(size_t)v * CD + c] = o - m - __logf(s);
}

extern "C" void kernel_launch(void* const* d_in, const int* in_sizes, int n_in,
                              void* d_out, int out_size, void* d_ws, size_t ws_size,
                              hipStream_t stream) {
    const float* x  = (const float*)d_in[0];
    const int*   ei = (const int*)d_in[1];   // [2, E] int32
    const float* W1 = (const float*)d_in[2];
    const float* b1 = (const float*)d_in[3];
    const float* W2 = (const float*)d_in[4];
    const float* b2 = (const float*)d_in[5];
    float* out = (float*)d_out;

    const int* src = ei;
    const int* dst = ei + NE;

    float* ws = (float*)d_ws;
    float* dinv   = ws;                        // NN floats
    int*   rowptr = (int*)(ws + 65536);        // NN ints
    int*   col    = (int*)(ws + 131072);       // NE ints
    int*   sums   = (int*)(ws + 931072);       // 64 ints
    float* hs1    = ws + 933888;               // NN*HD
    float* h1     = ws + 7333888;              // NN*HD
    float* hs2    = hs1;                       // reuse (hs1 dead after agg1)

    // ---- CSR build ----
    hipMemsetAsync(rowptr, 0, (size_t)NN * sizeof(int), stream);
    count_deg<<<(NE + 255) / 256, 256, 0, stream>>>(dst, rowptr);
    scan_a<<<NCHUNK, 1024, 0, stream>>>(rowptr, sums, dinv);
    scan_b<<<1, 64, 0, stream>>>(sums);
    scan_c<<<(NN + 255) / 256, 256, 0, stream>>>(rowptr, sums);
    fill_csr<<<(NE + 255) / 256, 256, 0, stream>>>(src, dst, rowptr, col);

    // ---- layer 1 ----
    gemm1<<<NN / 8, 256, 0, stream>>>(x, W1, dinv, hs1);
    agg1_csr<<<NN / 4, 256, 0, stream>>>(rowptr, col, hs1, dinv, b1, h1);

    // ---- layer 2 ----
    gemm2<<<NN / 16, 256, 0, stream>>>(h1, W2, dinv, hs2);
    agg2_csr<<<NN / 4, 256, 0, stream>>>(rowptr, col, hs2, dinv, b2, out);
}

// Round 7
// 290.659 us; speedup vs baseline: 6.2699x; 1.1065x over previous
//
#include <hip/hip_runtime.h>

#define NN 50000
#define NE 800000
#define DIN 128
#define HD 128
#define CD 64
#define NCHUNK ((NN + 1023) / 1024)  // 49

// ---------------- CSR build ----------------
__global__ void count_deg(const int* __restrict__ dst, int* __restrict__ cnt) {
    int e = blockIdx.x * blockDim.x + threadIdx.x;
    if (e < NE) atomicAdd(&cnt[dst[e]], 1);
}

// chunk-local exclusive scan + chunk totals; also emits dinv = rsqrt(cnt+2)
__global__ void __launch_bounds__(1024) scan_a(int* __restrict__ cnt, int* __restrict__ sums,
                                               float* __restrict__ dinv) {
    __shared__ int wsum[16];
    int t = threadIdx.x;
    int i = blockIdx.x * 1024 + t;
    int v = (i < NN) ? cnt[i] : 0;
    if (i < NN) dinv[i] = rsqrtf((float)(v + 2));  // +2 self loops
    int x = v;
#pragma unroll
    for (int off = 1; off < 64; off <<= 1) {
        int y = __shfl_up(x, off, 64);
        if ((t & 63) >= off) x += y;
    }
    int wid = t >> 6;
    if ((t & 63) == 63) wsum[wid] = x;
    __syncthreads();
    if (t < 16) {
        int s = wsum[t];
#pragma unroll
        for (int off = 1; off < 16; off <<= 1) {
            int y = __shfl_up(s, off, 16);
            if (t >= off) s += y;
        }
        wsum[t] = s;
    }
    __syncthreads();
    int base = (wid > 0) ? wsum[wid - 1] : 0;
    int incl = base + x;
    if (i < NN) cnt[i] = incl - v;  // exclusive within chunk
    if (t == 1023) sums[blockIdx.x] = incl;
}

__global__ void scan_b(int* __restrict__ sums) {
    int t = threadIdx.x;
    int v = (t < NCHUNK) ? sums[t] : 0;
    int x = v;
#pragma unroll
    for (int off = 1; off < 64; off <<= 1) {
        int y = __shfl_up(x, off, 64);
        if (t >= off) x += y;
    }
    if (t < NCHUNK) sums[t] = x - v;  // exclusive chunk bases
}

__global__ void scan_c(int* __restrict__ cnt, const int* __restrict__ sums) {
    int i = blockIdx.x * blockDim.x + threadIdx.x;
    if (i < NN) cnt[i] += sums[i >> 10];
}

// after fill: rowptr[v] == end offset of row v (start is rowptr[v-1])
__global__ void fill_csr(const int* __restrict__ src, const int* __restrict__ dst,
                         int* __restrict__ rowptr, int* __restrict__ col) {
    int e = blockIdx.x * blockDim.x + threadIdx.x;
    if (e < NE) {
        int d = dst[e];
        int pos = atomicAdd(&rowptr[d], 1);
        col[pos] = src[e];
    }
}

// ---------------- GEMM1: hs1 = dinv * (x @ W1) ----------------
// W1 in LDS (64 KB). Each wave: 8 uniform rows x 128 cols (float2/lane).
// x reads are wave-uniform -> s_load via readfirstlane; per k: 1 ds_read_b64 + 8 FMA2.
__global__ void __launch_bounds__(256) gemm1(const float* __restrict__ x, const float* __restrict__ W1,
                                             const float* __restrict__ dinv, float* __restrict__ hs1) {
    __shared__ float w[DIN * HD];  // 64 KB
    int t = threadIdx.x;
    {
        float4* wv = (float4*)w;
        const float4* Wg = (const float4*)W1;
        for (int i = t; i < DIN * HD / 4; i += 256) wv[i] = Wg[i];
    }
    __syncthreads();
    int lane = t & 63;
    int wid = t >> 6;
    int row0 = blockIdx.x * 32 + wid * 8;
    if (row0 > NN - 8) row0 = NN - 8;  // tail clamp: duplicate rows, identical values
    int urow = __builtin_amdgcn_readfirstlane(row0);
    const float* xr = x + (size_t)urow * DIN;

    float2 acc[8];
#pragma unroll
    for (int r = 0; r < 8; ++r) acc[r] = make_float2(0.f, 0.f);
    const float2* w2 = (const float2*)w;
#pragma unroll 4
    for (int k = 0; k < DIN; ++k) {
        float2 wk = w2[k * 64 + lane];
#pragma unroll
        for (int r = 0; r < 8; ++r) {
            float xv = xr[r * DIN + k];  // uniform -> SGPR
            acc[r].x += xv * wk.x;
            acc[r].y += xv * wk.y;
        }
    }
    float2* O = (float2*)hs1;
#pragma unroll
    for (int r = 0; r < 8; ++r) {
        float di = dinv[urow + r];
        float2 o;
        o.x = acc[r].x * di;
        o.y = acc[r].y * di;
        O[(size_t)(urow + r) * 64 + lane] = o;
    }
}

// ---------------- GEMM2: hs2 = dinv * (h1 @ W2) ----------------
// W2 in LDS (32 KB). Each wave: 8 uniform rows x 64 cols (1 col/lane).
__global__ void __launch_bounds__(256) gemm2(const float* __restrict__ h1, const float* __restrict__ W2,
                                             const float* __restrict__ dinv, float* __restrict__ hs2) {
    __shared__ float w[DIN * CD];  // 32 KB
    int t = threadIdx.x;
    {
        float4* wv = (float4*)w;
        const float4* Wg = (const float4*)W2;
        for (int i = t; i < DIN * CD / 4; i += 256) wv[i] = Wg[i];
    }
    __syncthreads();
    int lane = t & 63;
    int wid = t >> 6;
    int row0 = blockIdx.x * 32 + wid * 8;
    if (row0 > NN - 8) row0 = NN - 8;
    int urow = __builtin_amdgcn_readfirstlane(row0);
    const float* xr = h1 + (size_t)urow * DIN;

    float acc[8];
#pragma unroll
    for (int r = 0; r < 8; ++r) acc[r] = 0.f;
#pragma unroll 4
    for (int k = 0; k < DIN; ++k) {
        float wk = w[k * CD + lane];
#pragma unroll
        for (int r = 0; r < 8; ++r) acc[r] += xr[r * DIN + k] * wk;
    }
#pragma unroll
    for (int r = 0; r < 8; ++r)
        hs2[(size_t)(urow + r) * CD + lane] = acc[r] * dinv[urow + r];
}

// ---------------- agg1: CSR gather (float2/lane, one row per wave), unroll 4 ----------------
__global__ void agg1_csr(const int* __restrict__ rowptr, const int* __restrict__ col,
                         const float* __restrict__ hs1, const float* __restrict__ dinv,
                         const float* __restrict__ b1, float* __restrict__ h1) {
    int t = threadIdx.x;
    int v = blockIdx.x * 4 + (t >> 6);
    int c2 = t & 63;  // float2 lane
    const float2* H = (const float2*)hs1;  // row stride 64
    int start = (v == 0) ? 0 : rowptr[v - 1];
    int end = rowptr[v];
    float2 self = H[(size_t)v * 64 + c2];
    float ax = 2.f * self.x, ay = 2.f * self.y;
    int j = start;
    for (; j + 4 <= end; j += 4) {
        int s0 = col[j], s1 = col[j + 1], s2 = col[j + 2], s3 = col[j + 3];
        float2 v0 = H[(size_t)s0 * 64 + c2];
        float2 v1 = H[(size_t)s1 * 64 + c2];
        float2 v2 = H[(size_t)s2 * 64 + c2];
        float2 v3 = H[(size_t)s3 * 64 + c2];
        ax += v0.x + v1.x + v2.x + v3.x;
        ay += v0.y + v1.y + v2.y + v3.y;
    }
    for (; j < end; ++j) {
        float2 u = H[(size_t)col[j] * 64 + c2];
        ax += u.x; ay += u.y;
    }
    float di = dinv[v];
    int c = c2 * 2;
    float2 r;
    r.x = fmaxf(di * ax + b1[c], 0.f);
    r.y = fmaxf(di * ay + b1[c + 1], 0.f);
    ((float2*)h1)[(size_t)v * 64 + c2] = r;
}

// ---------------- agg2: CSR gather + bias + log_softmax (one wave per row), unroll 4 ----------------
__global__ void agg2_csr(const int* __restrict__ rowptr, const int* __restrict__ col,
                         const float* __restrict__ hs2, const float* __restrict__ dinv,
                         const float* __restrict__ b2, float* __restrict__ out) {
    int t = threadIdx.x;
    int v = blockIdx.x * 4 + (t >> 6);
    int c = t & 63;
    int start = (v == 0) ? 0 : rowptr[v - 1];
    int end = rowptr[v];
    float acc = 2.f * hs2[(size_t)v * CD + c];
    int j = start;
    for (; j + 4 <= end; j += 4) {
        int s0 = col[j], s1 = col[j + 1], s2 = col[j + 2], s3 = col[j + 3];
        acc += hs2[(size_t)s0 * CD + c] + hs2[(size_t)s1 * CD + c] +
               hs2[(size_t)s2 * CD + c] + hs2[(size_t)s3 * CD + c];
    }
    for (; j < end; ++j) acc += hs2[(size_t)col[j] * CD + c];
    float o = dinv[v] * acc + b2[c];
    float m = o;
#pragma unroll
    for (int off = 32; off >= 1; off >>= 1) m = fmaxf(m, __shfl_xor(m, off, 64));
    float ex = __expf(o - m);
    float s = ex;
#pragma unroll
    for (int off = 32; off >= 1; off >>= 1) s += __shfl_xor(s, off, 64);
    out[(size_t)v * CD + c] = o - m - __logf(s);
}

extern "C" void kernel_launch(void* const* d_in, const int* in_sizes, int n_in,
                              void* d_out, int out_size, void* d_ws, size_t ws_size,
                              hipStream_t stream) {
    const float* x  = (const float*)d_in[0];
    const int*   ei = (const int*)d_in[1];   // [2, E] int32
    const float* W1 = (const float*)d_in[2];
    const float* b1 = (const float*)d_in[3];
    const float* W2 = (const float*)d_in[4];
    const float* b2 = (const float*)d_in[5];
    float* out = (float*)d_out;

    const int* src = ei;
    const int* dst = ei + NE;

    float* ws = (float*)d_ws;
    float* dinv   = ws;                        // NN floats
    int*   rowptr = (int*)(ws + 65536);        // NN ints
    int*   col    = (int*)(ws + 131072);       // NE ints
    int*   sums   = (int*)(ws + 931072);       // 64 ints
    float* hs1    = ws + 933888;               // NN*HD
    float* h1     = ws + 7333888;              // NN*HD
    float* hs2    = hs1;                       // reuse (hs1 dead after agg1)

    // ---- CSR build ----
    hipMemsetAsync(rowptr, 0, (size_t)NN * sizeof(int), stream);
    count_deg<<<(NE + 255) / 256, 256, 0, stream>>>(dst, rowptr);
    scan_a<<<NCHUNK, 1024, 0, stream>>>(rowptr, sums, dinv);
    scan_b<<<1, 64, 0, stream>>>(sums);
    scan_c<<<(NN + 255) / 256, 256, 0, stream>>>(rowptr, sums);
    fill_csr<<<(NE + 255) / 256, 256, 0, stream>>>(src, dst, rowptr, col);

    // ---- layer 1 ----
    gemm1<<<(NN + 31) / 32, 256, 0, stream>>>(x, W1, dinv, hs1);
    agg1_csr<<<NN / 4, 256, 0, stream>>>(rowptr, col, hs1, dinv, b1, h1);

    // ---- layer 2 ----
    gemm2<<<(NN + 31) / 32, 256, 0, stream>>>(h1, W2, dinv, hs2);
    agg2_csr<<<NN / 4, 256, 0, stream>>>(rowptr, col, hs2, dinv, b2, out);
}

// Round 8
// 277.507 us; speedup vs baseline: 6.5670x; 1.0474x over previous
//
#include <hip/hip_runtime.h>

#define NN 50000
#define NE 800000
#define DIN 128
#define HD 128
#define CD 64
#define NCHUNK ((NN + 1023) / 1024)  // 49

// ---------------- CSR build ----------------
__global__ void count_deg(const int* __restrict__ dst, int* __restrict__ cnt) {
    int e = blockIdx.x * blockDim.x + threadIdx.x;
    if (e < NE) atomicAdd(&cnt[dst[e]], 1);
}

// chunk-local exclusive scan + chunk totals; also emits dinv = rsqrt(cnt+2)
__global__ void __launch_bounds__(1024) scan_a(int* __restrict__ cnt, int* __restrict__ sums,
                                               float* __restrict__ dinv) {
    __shared__ int wsum[16];
    int t = threadIdx.x;
    int i = blockIdx.x * 1024 + t;
    int v = (i < NN) ? cnt[i] : 0;
    if (i < NN) dinv[i] = rsqrtf((float)(v + 2));  // +2 self loops
    int x = v;
#pragma unroll
    for (int off = 1; off < 64; off <<= 1) {
        int y = __shfl_up(x, off, 64);
        if ((t & 63) >= off) x += y;
    }
    int wid = t >> 6;
    if ((t & 63) == 63) wsum[wid] = x;
    __syncthreads();
    if (t < 16) {
        int s = wsum[t];
#pragma unroll
        for (int off = 1; off < 16; off <<= 1) {
            int y = __shfl_up(s, off, 16);
            if (t >= off) s += y;
        }
        wsum[t] = s;
    }
    __syncthreads();
    int base = (wid > 0) ? wsum[wid - 1] : 0;
    int incl = base + x;
    if (i < NN) cnt[i] = incl - v;  // exclusive within chunk
    if (t == 1023) sums[blockIdx.x] = incl;
}

__global__ void scan_b(int* __restrict__ sums) {
    int t = threadIdx.x;
    int v = (t < NCHUNK) ? sums[t] : 0;
    int x = v;
#pragma unroll
    for (int off = 1; off < 64; off <<= 1) {
        int y = __shfl_up(x, off, 64);
        if (t >= off) x += y;
    }
    if (t < NCHUNK) sums[t] = x - v;  // exclusive chunk bases
}

__global__ void scan_c(int* __restrict__ cnt, const int* __restrict__ sums) {
    int i = blockIdx.x * blockDim.x + threadIdx.x;
    if (i < NN) cnt[i] += sums[i >> 10];
}

// after fill: rowptr[v] == end offset of row v (start is rowptr[v-1])
__global__ void fill_csr(const int* __restrict__ src, const int* __restrict__ dst,
                         int* __restrict__ rowptr, int* __restrict__ col) {
    int e = blockIdx.x * blockDim.x + threadIdx.x;
    if (e < NE) {
        int d = dst[e];
        int pos = atomicAdd(&rowptr[d], 1);
        col[pos] = src[e];
    }
}

// ---------------- GEMM1: hs1 = dinv * (x @ W1) ----------------
// W1 in LDS (64 KB). 512 threads = 8 waves; each wave 8 uniform rows x 128 cols
// (float2/lane). x reads wave-uniform -> s_load. 2 blocks/CU = 16 waves (VGPR cap).
__global__ void __launch_bounds__(512) gemm1(const float* __restrict__ x, const float* __restrict__ W1,
                                             const float* __restrict__ dinv, float* __restrict__ hs1) {
    __shared__ float w[DIN * HD];  // 64 KB
    int t = threadIdx.x;
    {
        float4* wv = (float4*)w;
        const float4* Wg = (const float4*)W1;
        for (int i = t; i < DIN * HD / 4; i += 512) wv[i] = Wg[i];
    }
    __syncthreads();
    int lane = t & 63;
    int wid = t >> 6;                       // 0..7
    int row0 = blockIdx.x * 64 + wid * 8;
    if (row0 > NN - 8) row0 = NN - 8;       // tail clamp: duplicate rows, identical values
    int urow = __builtin_amdgcn_readfirstlane(row0);
    const float* xr = x + (size_t)urow * DIN;

    float2 acc[8];
#pragma unroll
    for (int r = 0; r < 8; ++r) acc[r] = make_float2(0.f, 0.f);
    const float2* w2 = (const float2*)w;
#pragma unroll 4
    for (int k = 0; k < DIN; ++k) {
        float2 wk = w2[k * 64 + lane];
#pragma unroll
        for (int r = 0; r < 8; ++r) {
            float xv = xr[r * DIN + k];  // uniform -> SGPR
            acc[r].x += xv * wk.x;
            acc[r].y += xv * wk.y;
        }
    }
    float2* O = (float2*)hs1;
#pragma unroll
    for (int r = 0; r < 8; ++r) {
        float di = dinv[urow + r];
        float2 o;
        o.x = acc[r].x * di;
        o.y = acc[r].y * di;
        O[(size_t)(urow + r) * 64 + lane] = o;
    }
}

// ---------------- GEMM2: hs2 = dinv * (h1 @ W2) ----------------
// W2 in LDS (32 KB). 512 threads = 8 waves; each wave 8 uniform rows x 64 cols.
__global__ void __launch_bounds__(512) gemm2(const float* __restrict__ h1, const float* __restrict__ W2,
                                             const float* __restrict__ dinv, float* __restrict__ hs2) {
    __shared__ float w[DIN * CD];  // 32 KB
    int t = threadIdx.x;
    {
        float4* wv = (float4*)w;
        const float4* Wg = (const float4*)W2;
        for (int i = t; i < DIN * CD / 4; i += 512) wv[i] = Wg[i];
    }
    __syncthreads();
    int lane = t & 63;
    int wid = t >> 6;
    int row0 = blockIdx.x * 64 + wid * 8;
    if (row0 > NN - 8) row0 = NN - 8;
    int urow = __builtin_amdgcn_readfirstlane(row0);
    const float* xr = h1 + (size_t)urow * DIN;

    float acc[8];
#pragma unroll
    for (int r = 0; r < 8; ++r) acc[r] = 0.f;
#pragma unroll 4
    for (int k = 0; k < DIN; ++k) {
        float wk = w[k * CD + lane];
#pragma unroll
        for (int r = 0; r < 8; ++r) acc[r] += xr[r * DIN + k] * wk;
    }
#pragma unroll
    for (int r = 0; r < 8; ++r)
        hs2[(size_t)(urow + r) * CD + lane] = acc[r] * dinv[urow + r];
}

// ---------------- agg1: CSR gather (float2/lane, one row per wave), unroll 4 ----------------
__global__ void agg1_csr(const int* __restrict__ rowptr, const int* __restrict__ col,
                         const float* __restrict__ hs1, const float* __restrict__ dinv,
                         const float* __restrict__ b1, float* __restrict__ h1) {
    int t = threadIdx.x;
    int v = blockIdx.x * 4 + (t >> 6);
    int c2 = t & 63;  // float2 lane
    const float2* H = (const float2*)hs1;  // row stride 64
    int start = (v == 0) ? 0 : rowptr[v - 1];
    int end = rowptr[v];
    float2 self = H[(size_t)v * 64 + c2];
    float ax = 2.f * self.x, ay = 2.f * self.y;
    int j = start;
    for (; j + 4 <= end; j += 4) {
        int s0 = col[j], s1 = col[j + 1], s2 = col[j + 2], s3 = col[j + 3];
        float2 v0 = H[(size_t)s0 * 64 + c2];
        float2 v1 = H[(size_t)s1 * 64 + c2];
        float2 v2 = H[(size_t)s2 * 64 + c2];
        float2 v3 = H[(size_t)s3 * 64 + c2];
        ax += v0.x + v1.x + v2.x + v3.x;
        ay += v0.y + v1.y + v2.y + v3.y;
    }
    for (; j < end; ++j) {
        float2 u = H[(size_t)col[j] * 64 + c2];
        ax += u.x; ay += u.y;
    }
    float di = dinv[v];
    int c = c2 * 2;
    float2 r;
    r.x = fmaxf(di * ax + b1[c], 0.f);
    r.y = fmaxf(di * ay + b1[c + 1], 0.f);
    ((float2*)h1)[(size_t)v * 64 + c2] = r;
}

// ---------------- agg2: CSR gather + bias + log_softmax (one wave per row), unroll 4 ----------------
__global__ void agg2_csr(const int* __restrict__ rowptr, const int* __restrict__ col,
                         const float* __restrict__ hs2, const float* __restrict__ dinv,
                         const float* __restrict__ b2, float* __restrict__ out) {
    int t = threadIdx.x;
    int v = blockIdx.x * 4 + (t >> 6);
    int c = t & 63;
    int start = (v == 0) ? 0 : rowptr[v - 1];
    int end = rowptr[v];
    float acc = 2.f * hs2[(size_t)v * CD + c];
    int j = start;
    for (; j + 4 <= end; j += 4) {
        int s0 = col[j], s1 = col[j + 1], s2 = col[j + 2], s3 = col[j + 3];
        acc += hs2[(size_t)s0 * CD + c] + hs2[(size_t)s1 * CD + c] +
               hs2[(size_t)s2 * CD + c] + hs2[(size_t)s3 * CD + c];
    }
    for (; j < end; ++j) acc += hs2[(size_t)col[j] * CD + c];
    float o = dinv[v] * acc + b2[c];
    float m = o;
#pragma unroll
    for (int off = 32; off >= 1; off >>= 1) m = fmaxf(m, __shfl_xor(m, off, 64));
    float ex = __expf(o - m);
    float s = ex;
#pragma unroll
    for (int off = 32; off >= 1; off >>= 1) s += __shfl_xor(s, off, 64);
    out[(size_t)v * CD + c] = o - m - __logf(s);
}

extern "C" void kernel_launch(void* const* d_in, const int* in_sizes, int n_in,
                              void* d_out, int out_size, void* d_ws, size_t ws_size,
                              hipStream_t stream) {
    const float* x  = (const float*)d_in[0];
    const int*   ei = (const int*)d_in[1];   // [2, E] int32
    const float* W1 = (const float*)d_in[2];
    const float* b1 = (const float*)d_in[3];
    const float* W2 = (const float*)d_in[4];
    const float* b2 = (const float*)d_in[5];
    float* out = (float*)d_out;

    const int* src = ei;
    const int* dst = ei + NE;

    float* ws = (float*)d_ws;
    float* dinv   = ws;                        // NN floats
    int*   rowptr = (int*)(ws + 65536);        // NN ints
    int*   col    = (int*)(ws + 131072);       // NE ints
    int*   sums   = (int*)(ws + 931072);       // 64 ints
    float* hs1    = ws + 933888;               // NN*HD
    float* h1     = ws + 7333888;              // NN*HD
    float* hs2    = hs1;                       // reuse (hs1 dead after agg1)

    // ---- CSR build ----
    hipMemsetAsync(rowptr, 0, (size_t)NN * sizeof(int), stream);
    count_deg<<<(NE + 255) / 256, 256, 0, stream>>>(dst, rowptr);
    scan_a<<<NCHUNK, 1024, 0, stream>>>(rowptr, sums, dinv);
    scan_b<<<1, 64, 0, stream>>>(sums);
    scan_c<<<(NN + 255) / 256, 256, 0, stream>>>(rowptr, sums);
    fill_csr<<<(NE + 255) / 256, 256, 0, stream>>>(src, dst, rowptr, col);

    // ---- layer 1 ----
    gemm1<<<(NN + 63) / 64, 512, 0, stream>>>(x, W1, dinv, hs1);
    agg1_csr<<<NN / 4, 256, 0, stream>>>(rowptr, col, hs1, dinv, b1, h1);

    // ---- layer 2 ----
    gemm2<<<(NN + 63) / 64, 512, 0, stream>>>(h1, W2, dinv, hs2);
    agg2_csr<<<NN / 4, 256, 0, stream>>>(rowptr, col, hs2, dinv, b2, out);
}